// Round 1
// baseline (576.361 us; speedup 1.0000x reference)
//
#include <hip/hip_runtime.h>
#include <hip/hip_bf16.h>

typedef unsigned short u16;
typedef __bf16 bf16x8 __attribute__((ext_vector_type(8)));
typedef float f32x4 __attribute__((ext_vector_type(4)));

#define NN 20000
#define NE 320000

// ---------------- ws layout (bytes) ----------------
constexpr size_t SZ_W1  = (size_t)9  * 34 * 512 * 2;   // eW1  swz: K 288, N 544
constexpr size_t SZ_W2  = (size_t)17 * 8  * 512 * 2;   // eW2  swz: K 544, N 128
constexpr size_t SZ_WC1 = (size_t)4  * 16 * 512 * 2;   // cW1  swz: K 128, N 256
constexpr size_t SZ_WC2 = (size_t)8  * 1  * 512 * 2;   // cW2  swz: K 256, N 16
constexpr size_t SZ_WN1 = (size_t)8  * 32 * 512 * 2;   // nW1  swz: K 256, N 512
constexpr size_t SZ_WN2 = (size_t)16 * 8  * 512 * 2;   // nW2  swz: K 512, N 128
constexpr size_t OFF_W1   = 0;
constexpr size_t OFF_W2   = OFF_W1 + SZ_W1;
constexpr size_t OFF_WC1  = OFF_W2 + SZ_W2;
constexpr size_t OFF_WC2  = OFF_WC1 + SZ_WC1;
constexpr size_t OFF_WN1  = OFF_WC2 + SZ_WC2;
constexpr size_t OFF_WN2  = OFF_WN1 + SZ_WN1;
constexpr size_t OFF_HB   = OFF_WN2 + SZ_WN2;          // h as bf16 [NN,128]
constexpr size_t SZ_HB    = (size_t)NN * 128 * 2;
constexpr size_t OFF_AGGH = OFF_HB + SZ_HB;            // f32 [NN,128]
constexpr size_t SZ_AGGH  = (size_t)NN * 128 * 4;
constexpr size_t OFF_AGGC = OFF_AGGH + SZ_AGGH;        // f32 [NN,9]
constexpr size_t SZ_AGGC  = (size_t)NN * 9 * 4;
constexpr size_t OFF_CNT  = OFF_AGGC + SZ_AGGC;        // f32 [NN]
constexpr size_t SZ_CNT   = (size_t)NN * 4;

__device__ __forceinline__ u16 f2b(float x) {
  union { float f; unsigned u; } v; v.f = x;
  unsigned r = (v.u + 0x7fffu + ((v.u >> 16) & 1u)) >> 16;
  return (u16)r;
}
__device__ __forceinline__ float silu_f(float x) { return x / (1.f + __expf(-x)); }

// Pre-swizzle a f32 [Kreal][Nreal] weight into MFMA B-fragment order, bf16.
// dst[((nt*KT+kt)*64 + lane)*8 + e] = W[kt*32 + (lane>>4)*8 + e][nt*16 + (lane&15)]
__global__ void swz_kernel(const float* __restrict__ W, u16* __restrict__ dst,
                           int Kreal, int Nreal, int KT, int NT) {
  int idx = blockIdx.x * 256 + threadIdx.x;
  int total = KT * NT * 512;
  if (idx >= total) return;
  int e = idx & 7, l = (idx >> 3) & 63, blk = idx >> 9;
  int kt = blk % KT, nt = blk / KT;
  int k = kt * 32 + ((l >> 4) * 8) + e;
  int n = nt * 16 + (l & 15);
  float v = (k < Kreal && n < Nreal) ? W[(size_t)k * Nreal + n] : 0.f;
  dst[idx] = f2b(v);
}

__global__ void tob16_kernel(const float* __restrict__ x, u16* __restrict__ y, int n) {
  int i = blockIdx.x * 256 + threadIdx.x;
  if (i < n) y[i] = f2b(x[i]);
}

// ---------------- fused edge pipeline ----------------
__global__ __launch_bounds__(512)
void edge_kernel(const u16* __restrict__ hb, const int* __restrict__ eidx,
                 const float* __restrict__ coord,
                 const u16* __restrict__ W1s, const float* __restrict__ b1,
                 const u16* __restrict__ W2s, const float* __restrict__ b2,
                 const u16* __restrict__ WC1s, const float* __restrict__ bc1,
                 const u16* __restrict__ WC2s,
                 float* __restrict__ agg_h, float* __restrict__ agg_c,
                 float* __restrict__ cnt) {
  // one buffer reused: A1 [64][296] -> Y1 [64][552] -> A3 [64][136] -> Y3 [64][264]
  __shared__ __align__(16) u16 buf[64 * 552];
  __shared__ float cd_s[64][9];
  __shared__ float phi_s[64][3];
  __shared__ int row_s[64];
  __shared__ int col_s[64];

  const int tid = threadIdx.x;
  const int lane = tid & 63;
  const int w = tid >> 6;
  const int l_lo = lane & 15;
  const int l_hi = lane >> 4;
  const int e0 = blockIdx.x << 6;

  if (tid < 64) {
    row_s[tid] = eidx[e0 + tid];
    col_s[tid] = eidx[NE + e0 + tid];
  }
  __syncthreads();

  // radial + K-pad zeros (wave 0), h gather (all waves)
  if (tid < 64) {
    const int r = row_s[tid], c = col_s[tid];
    float cd[9];
    #pragma unroll
    for (int i = 0; i < 9; i++) { cd[i] = coord[r * 9 + i] - coord[c * 9 + i]; cd_s[tid][i] = cd[i]; }
    u16* arow = buf + tid * 296;
    #pragma unroll
    for (int a = 0; a < 3; a++)
      #pragma unroll
      for (int b = 0; b < 3; b++) {
        float rad = cd[a*3]*cd[b*3] + cd[a*3+1]*cd[b*3+1] + cd[a*3+2]*cd[b*3+2];
        arow[256 + a * 3 + b] = f2b(rad);
      }
    #pragma unroll
    for (int k = 265; k < 288; k++) arow[k] = (u16)0;
  }
  for (int q = tid; q < 2048; q += 512) {
    const int e = q >> 5, sub = q & 31, which = sub >> 4, j = sub & 15;
    const int node = which ? col_s[e] : row_s[e];
    const int4 v = *reinterpret_cast<const int4*>(hb + (size_t)node * 128 + j * 8);
    *reinterpret_cast<int4*>(buf + e * 296 + which * 128 + j * 8) = v;
  }
  __syncthreads();

  // GEMM1: [64,288] x [288,544]; wave w owns n-tiles w, w+8, ...
  f32x4 acc1[5][4];
  #pragma unroll
  for (int i = 0; i < 5; i++)
    #pragma unroll
    for (int m = 0; m < 4; m++) acc1[i][m] = {0.f, 0.f, 0.f, 0.f};
  for (int kt = 0; kt < 9; kt++) {
    bf16x8 af[4];
    #pragma unroll
    for (int m = 0; m < 4; m++)
      af[m] = *reinterpret_cast<const bf16x8*>(buf + (m * 16 + l_lo) * 296 + kt * 32 + l_hi * 8);
    #pragma unroll
    for (int i = 0; i < 5; i++) {
      const int nt = w + 8 * i;
      if (nt < 34) {
        const bf16x8 bfr = *reinterpret_cast<const bf16x8*>(W1s + (((nt * 9 + kt) << 6) + lane) * 8);
        #pragma unroll
        for (int m = 0; m < 4; m++)
          acc1[i][m] = __builtin_amdgcn_mfma_f32_16x16x32_bf16(af[m], bfr, acc1[i][m], 0, 0, 0);
      }
    }
  }
  __syncthreads();
  #pragma unroll
  for (int i = 0; i < 5; i++) {
    const int nt = w + 8 * i;
    if (nt < 34) {
      const int coln = nt * 16 + l_lo;
      const float bias = (coln < 530) ? b1[coln] : 0.f;
      #pragma unroll
      for (int m = 0; m < 4; m++)
        #pragma unroll
        for (int r = 0; r < 4; r++) {
          const int row = m * 16 + l_hi * 4 + r;
          buf[row * 552 + coln] = f2b(silu_f(acc1[i][m][r] + bias));
        }
    }
  }
  __syncthreads();

  // GEMM2: [64,544] x [544,128]; wave w owns n-tile w
  f32x4 acc2[4];
  #pragma unroll
  for (int m = 0; m < 4; m++) acc2[m] = {0.f, 0.f, 0.f, 0.f};
  for (int kt = 0; kt < 17; kt++) {
    const bf16x8 bfr = *reinterpret_cast<const bf16x8*>(W2s + (((w * 17 + kt) << 6) + lane) * 8);
    #pragma unroll
    for (int m = 0; m < 4; m++) {
      const bf16x8 af = *reinterpret_cast<const bf16x8*>(buf + (m * 16 + l_lo) * 552 + kt * 32 + l_hi * 8);
      acc2[m] = __builtin_amdgcn_mfma_f32_16x16x32_bf16(af, bfr, acc2[m], 0, 0, 0);
    }
  }
  __syncthreads();
  {
    const int coln = w * 16 + l_lo;
    const float bias = b2[coln];
    #pragma unroll
    for (int m = 0; m < 4; m++)
      #pragma unroll
      for (int r = 0; r < 4; r++) {
        const int el = m * 16 + l_hi * 4 + r;
        const float ef = silu_f(acc2[m][r] + bias);
        buf[el * 136 + coln] = f2b(ef);                       // A3 = edge_feat (bf16)
        atomicAdd(&agg_h[(size_t)row_s[el] * 128 + coln], ef); // segment-sum (f32)
      }
  }
  __syncthreads();

  // GEMM3: [64,128] x [128,256]; wave w owns n-tiles w, w+8
  f32x4 acc3[2][4];
  #pragma unroll
  for (int i = 0; i < 2; i++)
    #pragma unroll
    for (int m = 0; m < 4; m++) acc3[i][m] = {0.f, 0.f, 0.f, 0.f};
  for (int kt = 0; kt < 4; kt++) {
    bf16x8 af[4];
    #pragma unroll
    for (int m = 0; m < 4; m++)
      af[m] = *reinterpret_cast<const bf16x8*>(buf + (m * 16 + l_lo) * 136 + kt * 32 + l_hi * 8);
    #pragma unroll
    for (int i = 0; i < 2; i++) {
      const int nt = w + 8 * i;
      const bf16x8 bfr = *reinterpret_cast<const bf16x8*>(WC1s + (((nt * 4 + kt) << 6) + lane) * 8);
      #pragma unroll
      for (int m = 0; m < 4; m++)
        acc3[i][m] = __builtin_amdgcn_mfma_f32_16x16x32_bf16(af[m], bfr, acc3[i][m], 0, 0, 0);
    }
  }
  __syncthreads();
  #pragma unroll
  for (int i = 0; i < 2; i++) {
    const int nt = w + 8 * i;
    const int coln = nt * 16 + l_lo;
    const float bias = bc1[coln];
    #pragma unroll
    for (int m = 0; m < 4; m++)
      #pragma unroll
      for (int r = 0; r < 4; r++) {
        const int row = m * 16 + l_hi * 4 + r;
        buf[row * 264 + coln] = f2b(silu_f(acc3[i][m][r] + bias));  // Y3
      }
  }
  __syncthreads();

  // GEMM4: [64,256] x [256,16] (cols 0..2 real); waves 0..3, m-tile = w
  if (w < 4) {
    f32x4 acc4 = {0.f, 0.f, 0.f, 0.f};
    for (int kt = 0; kt < 8; kt++) {
      const bf16x8 af = *reinterpret_cast<const bf16x8*>(buf + (w * 16 + l_lo) * 264 + kt * 32 + l_hi * 8);
      const bf16x8 bfr = *reinterpret_cast<const bf16x8*>(WC2s + ((kt << 6) + lane) * 8);
      acc4 = __builtin_amdgcn_mfma_f32_16x16x32_bf16(af, bfr, acc4, 0, 0, 0);
    }
    if (l_lo < 3) {
      #pragma unroll
      for (int r = 0; r < 4; r++) phi_s[w * 16 + l_hi * 4 + r][l_lo] = acc4[r];
    }
  }
  __syncthreads();

  if (tid < 64) {
    const int node = row_s[tid];
    const float p0 = phi_s[tid][0], p1 = phi_s[tid][1], p2 = phi_s[tid][2];
    #pragma unroll
    for (int d = 0; d < 3; d++) {
      atomicAdd(&agg_c[(size_t)node * 9 + 0 + d], cd_s[tid][0 + d] * p0);
      atomicAdd(&agg_c[(size_t)node * 9 + 3 + d], cd_s[tid][3 + d] * p1);
      atomicAdd(&agg_c[(size_t)node * 9 + 6 + d], cd_s[tid][6 + d] * p2);
    }
    atomicAdd(&cnt[node], 1.f);
  }
}

// ---------------- node MLP ----------------
__global__ __launch_bounds__(512)
void node_kernel(const float* __restrict__ h, const u16* __restrict__ hb,
                 const float* __restrict__ agg_h,
                 const u16* __restrict__ WN1s, const float* __restrict__ nb1,
                 const u16* __restrict__ WN2s, const float* __restrict__ nb2,
                 float* __restrict__ out) {
  __shared__ __align__(16) u16 buf[64 * 520];  // A [64][264] then Y1 [64][520]
  const int tid = threadIdx.x;
  const int lane = tid & 63;
  const int w = tid >> 6;
  const int l_lo = lane & 15;
  const int l_hi = lane >> 4;
  const int n0 = blockIdx.x << 6;

  for (int q = tid; q < 1024; q += 512) {
    const int e = q >> 4, j = q & 15;
    const int row = n0 + e;
    int4 v;
    if (row < NN) v = *reinterpret_cast<const int4*>(hb + (size_t)row * 128 + j * 8);
    else { v.x = v.y = v.z = v.w = 0; }
    *reinterpret_cast<int4*>(buf + e * 264 + j * 8) = v;
  }
  for (int q = tid; q < 8192; q += 512) {
    const int e = q >> 7, k = q & 127;
    const int row = n0 + e;
    const float v = (row < NN) ? agg_h[(size_t)row * 128 + k] : 0.f;
    buf[e * 264 + 128 + k] = f2b(v);
  }
  __syncthreads();

  // GEMM5: [64,256] x [256,512]; wave w owns n-tiles w, w+8, w+16, w+24
  f32x4 acc[4][4];
  #pragma unroll
  for (int i = 0; i < 4; i++)
    #pragma unroll
    for (int m = 0; m < 4; m++) acc[i][m] = {0.f, 0.f, 0.f, 0.f};
  for (int kt = 0; kt < 8; kt++) {
    bf16x8 af[4];
    #pragma unroll
    for (int m = 0; m < 4; m++)
      af[m] = *reinterpret_cast<const bf16x8*>(buf + (m * 16 + l_lo) * 264 + kt * 32 + l_hi * 8);
    #pragma unroll
    for (int i = 0; i < 4; i++) {
      const int nt = w + 8 * i;
      const bf16x8 bfr = *reinterpret_cast<const bf16x8*>(WN1s + (((nt * 8 + kt) << 6) + lane) * 8);
      #pragma unroll
      for (int m = 0; m < 4; m++)
        acc[i][m] = __builtin_amdgcn_mfma_f32_16x16x32_bf16(af[m], bfr, acc[i][m], 0, 0, 0);
    }
  }
  __syncthreads();
  #pragma unroll
  for (int i = 0; i < 4; i++) {
    const int nt = w + 8 * i;
    const int coln = nt * 16 + l_lo;
    const float bias = nb1[coln];
    #pragma unroll
    for (int m = 0; m < 4; m++)
      #pragma unroll
      for (int r = 0; r < 4; r++) {
        const int row = m * 16 + l_hi * 4 + r;
        buf[row * 520 + coln] = f2b(silu_f(acc[i][m][r] + bias));
      }
  }
  __syncthreads();

  // GEMM6: [64,512] x [512,128]; wave w owns n-tile w
  f32x4 acc2[4];
  #pragma unroll
  for (int m = 0; m < 4; m++) acc2[m] = {0.f, 0.f, 0.f, 0.f};
  for (int kt = 0; kt < 16; kt++) {
    const bf16x8 bfr = *reinterpret_cast<const bf16x8*>(WN2s + (((w * 16 + kt) << 6) + lane) * 8);
    #pragma unroll
    for (int m = 0; m < 4; m++) {
      const bf16x8 af = *reinterpret_cast<const bf16x8*>(buf + (m * 16 + l_lo) * 520 + kt * 32 + l_hi * 8);
      acc2[m] = __builtin_amdgcn_mfma_f32_16x16x32_bf16(af, bfr, acc2[m], 0, 0, 0);
    }
  }
  {
    const int coln = w * 16 + l_lo;
    const float bias = nb2[coln];
    #pragma unroll
    for (int m = 0; m < 4; m++)
      #pragma unroll
      for (int r = 0; r < 4; r++) {
        const int row = n0 + m * 16 + l_hi * 4 + r;
        if (row < NN)
          out[(size_t)row * 128 + coln] = h[(size_t)row * 128 + coln] + silu_f(acc2[m][r] + bias);
      }
  }
}

__global__ void coord_kernel(const float* __restrict__ coord, const float* __restrict__ agg_c,
                             const float* __restrict__ cnt, float* __restrict__ out) {
  int i = blockIdx.x * 256 + threadIdx.x;
  if (i < NN * 9) {
    float c = fmaxf(cnt[i / 9], 1.f);
    float v = agg_c[i] / c;
    v = fminf(fmaxf(v, -10.f), 10.f);
    out[i] = coord[i] + v;
  }
}

extern "C" void kernel_launch(void* const* d_in, const int* in_sizes, int n_in,
                              void* d_out, int out_size, void* d_ws, size_t ws_size,
                              hipStream_t stream) {
  (void)in_sizes; (void)n_in; (void)out_size; (void)ws_size;
  const float* h     = (const float*)d_in[0];
  const int*   eidx  = (const int*)d_in[1];
  const float* coord = (const float*)d_in[2];
  const float* eW1 = (const float*)d_in[3];  const float* eb1 = (const float*)d_in[4];
  const float* eW2 = (const float*)d_in[5];  const float* eb2 = (const float*)d_in[6];
  const float* nW1 = (const float*)d_in[7];  const float* nb1 = (const float*)d_in[8];
  const float* nW2 = (const float*)d_in[9];  const float* nb2 = (const float*)d_in[10];
  const float* cW1 = (const float*)d_in[11]; const float* cb1 = (const float*)d_in[12];
  const float* cW2 = (const float*)d_in[13];

  char* ws = (char*)d_ws;
  u16* W1s  = (u16*)(ws + OFF_W1);
  u16* W2s  = (u16*)(ws + OFF_W2);
  u16* WC1s = (u16*)(ws + OFF_WC1);
  u16* WC2s = (u16*)(ws + OFF_WC2);
  u16* WN1s = (u16*)(ws + OFF_WN1);
  u16* WN2s = (u16*)(ws + OFF_WN2);
  u16* hb   = (u16*)(ws + OFF_HB);
  float* agg_h = (float*)(ws + OFF_AGGH);
  float* agg_c = (float*)(ws + OFF_AGGC);
  float* cnt   = (float*)(ws + OFF_CNT);
  float* out   = (float*)d_out;

  hipMemsetAsync(ws + OFF_AGGH, 0, SZ_AGGH + SZ_AGGC + SZ_CNT, stream);

  swz_kernel<<<9 * 34 * 2, 256, 0, stream>>>(eW1, W1s, 265, 530, 9, 34);
  swz_kernel<<<17 * 8 * 2, 256, 0, stream>>>(eW2, W2s, 530, 128, 17, 8);
  swz_kernel<<<4 * 16 * 2, 256, 0, stream>>>(cW1, WC1s, 128, 256, 4, 16);
  swz_kernel<<<8 * 1 * 2, 256, 0, stream>>>(cW2, WC2s, 256, 3, 8, 1);
  swz_kernel<<<8 * 32 * 2, 256, 0, stream>>>(nW1, WN1s, 256, 512, 8, 32);
  swz_kernel<<<16 * 8 * 2, 256, 0, stream>>>(nW2, WN2s, 512, 128, 16, 8);
  tob16_kernel<<<(NN * 128 + 255) / 256, 256, 0, stream>>>(h, hb, NN * 128);

  edge_kernel<<<NE / 64, 512, 0, stream>>>(hb, eidx, coord, W1s, eb1, W2s, eb2,
                                           WC1s, cb1, WC2s, agg_h, agg_c, cnt);
  node_kernel<<<(NN + 63) / 64, 512, 0, stream>>>(h, hb, agg_h, WN1s, nb1, WN2s, nb2, out);
  coord_kernel<<<(NN * 9 + 255) / 256, 256, 0, stream>>>(coord, agg_c, cnt, out + (size_t)NN * 128);
}

// Round 2
// 424.160 us; speedup vs baseline: 1.3588x; 1.3588x over previous
//
#include <hip/hip_runtime.h>
#include <hip/hip_bf16.h>

typedef unsigned short u16;
typedef __bf16 bf16x8 __attribute__((ext_vector_type(8)));
typedef float f32x4 __attribute__((ext_vector_type(4)));

#define NN 20000
#define NE 320000

// ---------------- ws layout (bytes) ----------------
constexpr size_t SZ_W1  = (size_t)9  * 34 * 512 * 2;   // eW1  swz: K 288, N 544
constexpr size_t SZ_W2  = (size_t)17 * 8  * 512 * 2;   // eW2  swz: K 544, N 128
constexpr size_t SZ_WC1 = (size_t)4  * 16 * 512 * 2;   // cW1  swz: K 128, N 256
constexpr size_t SZ_WC2 = (size_t)8  * 1  * 512 * 2;   // cW2  swz: K 256, N 16
constexpr size_t SZ_WN1 = (size_t)8  * 32 * 512 * 2;   // nW1  swz: K 256, N 512
constexpr size_t SZ_WN2 = (size_t)16 * 8  * 512 * 2;   // nW2  swz: K 512, N 128
constexpr size_t OFF_W1   = 0;
constexpr size_t OFF_W2   = OFF_W1 + SZ_W1;
constexpr size_t OFF_WC1  = OFF_W2 + SZ_W2;
constexpr size_t OFF_WC2  = OFF_WC1 + SZ_WC1;
constexpr size_t OFF_WN1  = OFF_WC2 + SZ_WC2;
constexpr size_t OFF_WN2  = OFF_WN1 + SZ_WN1;
constexpr size_t OFF_HB   = OFF_WN2 + SZ_WN2;          // h as bf16 [NN,128]
constexpr size_t SZ_HB    = (size_t)NN * 128 * 2;
constexpr size_t OFF_AGGH = OFF_HB + SZ_HB;            // f32 [NN,128]
constexpr size_t SZ_AGGH  = (size_t)NN * 128 * 4;
constexpr size_t OFF_AGGC = OFF_AGGH + SZ_AGGH;        // f32 [NN,9]
constexpr size_t SZ_AGGC  = (size_t)NN * 9 * 4;
constexpr size_t OFF_CNT  = OFF_AGGC + SZ_AGGC;        // f32 [NN]
constexpr size_t SZ_CNT   = (size_t)NN * 4;

__device__ __forceinline__ u16 f2b(float x) {
  union { float f; unsigned u; } v; v.f = x;
  unsigned r = (v.u + 0x7fffu + ((v.u >> 16) & 1u)) >> 16;
  return (u16)r;
}
// silu via hardware exp2 + rcp approx (bf16-accuracy is plenty)
__device__ __forceinline__ float silu_f(float x) {
  float e = __builtin_amdgcn_exp2f(-1.44269504088896f * x);
  return x * __builtin_amdgcn_rcpf(1.f + e);
}

// Pre-swizzle a f32 [Kreal][Nreal] weight into MFMA B-fragment order, bf16.
// dst[((nt*KT+kt)*64 + lane)*8 + e] = W[kt*32 + (lane>>4)*8 + e][nt*16 + (lane&15)]
__global__ void swz_kernel(const float* __restrict__ W, u16* __restrict__ dst,
                           int Kreal, int Nreal, int KT, int NT) {
  int idx = blockIdx.x * 256 + threadIdx.x;
  int total = KT * NT * 512;
  if (idx >= total) return;
  int e = idx & 7, l = (idx >> 3) & 63, blk = idx >> 9;
  int kt = blk % KT, nt = blk / KT;
  int k = kt * 32 + ((l >> 4) * 8) + e;
  int n = nt * 16 + (l & 15);
  float v = (k < Kreal && n < Nreal) ? W[(size_t)k * Nreal + n] : 0.f;
  dst[idx] = f2b(v);
}

__global__ void tob16_kernel(const float* __restrict__ x, u16* __restrict__ y, int n) {
  int i = blockIdx.x * 256 + threadIdx.x;
  if (i < n) y[i] = f2b(x[i]);
}

// ---------------- fused edge pipeline (N-chunked GEMM1->GEMM2 for low regs) ----------------
__global__ __launch_bounds__(512, 4)
void edge_kernel(const u16* __restrict__ hb, const int* __restrict__ eidx,
                 const float* __restrict__ coord,
                 const u16* __restrict__ W1s, const float* __restrict__ b1,
                 const u16* __restrict__ W2s, const float* __restrict__ b2,
                 const u16* __restrict__ WC1s, const float* __restrict__ bc1,
                 const u16* __restrict__ WC2s,
                 float* __restrict__ agg_h, float* __restrict__ agg_c,
                 float* __restrict__ cnt) {
  // bufA: A1 [64][296] (K 288 + pad) -> later Y3 [64][264]
  // bufB: Y1 chunk [64][136] (8 n-tiles of 16 + pad) -> later ef/A3 [64][136]
  __shared__ __align__(16) u16 bufA[64 * 296];
  __shared__ __align__(16) u16 bufB[64 * 136];
  __shared__ float cd_s[64][9];
  __shared__ float phi_s[64][3];
  __shared__ int row_s[64];
  __shared__ int col_s[64];

  const int tid = threadIdx.x;
  const int lane = tid & 63;
  const int w = tid >> 6;
  const int l_lo = lane & 15;
  const int l_hi = lane >> 4;
  const int e0 = blockIdx.x << 6;

  if (tid < 64) row_s[tid] = eidx[e0 + tid];
  else if (tid < 128) col_s[tid - 64] = eidx[NE + e0 + tid - 64];
  __syncthreads();

  // radial + K-pad zeros (wave 0), h gather (all waves) -> bufA
  if (tid < 64) {
    const int r = row_s[tid], c = col_s[tid];
    float cd[9];
    #pragma unroll
    for (int i = 0; i < 9; i++) { cd[i] = coord[r * 9 + i] - coord[c * 9 + i]; cd_s[tid][i] = cd[i]; }
    u16* arow = bufA + tid * 296;
    #pragma unroll
    for (int a = 0; a < 3; a++)
      #pragma unroll
      for (int b = 0; b < 3; b++) {
        float rad = cd[a*3]*cd[b*3] + cd[a*3+1]*cd[b*3+1] + cd[a*3+2]*cd[b*3+2];
        arow[256 + a * 3 + b] = f2b(rad);
      }
    #pragma unroll
    for (int k = 265; k < 288; k++) arow[k] = (u16)0;
  }
  for (int q = tid; q < 2048; q += 512) {
    const int e = q >> 5, sub = q & 31, which = sub >> 4, j = sub & 15;
    const int node = which ? col_s[e] : row_s[e];
    const int4 v = *reinterpret_cast<const int4*>(hb + (size_t)node * 128 + j * 8);
    *reinterpret_cast<int4*>(bufA + e * 296 + which * 128 + j * 8) = v;
  }
  __syncthreads();

  // Chunked GEMM1 [64,288]x[288,544] -> silu -> GEMM2 [64,544]x[544,128]
  // chunk c covers Y1 n-tiles [8c, 8c+8) (wave w does tile 8c+w), i.e. GEMM2
  // k-tiles [4c, min(4c+4,17)).
  f32x4 acc2[4];
  #pragma unroll
  for (int m = 0; m < 4; m++) acc2[m] = {0.f, 0.f, 0.f, 0.f};

  for (int c = 0; c < 5; c++) {
    const int nt = 8 * c + w;
    f32x4 acc1[4];
    #pragma unroll
    for (int m = 0; m < 4; m++) acc1[m] = {0.f, 0.f, 0.f, 0.f};
    if (nt < 34) {
      for (int kt = 0; kt < 9; kt++) {
        const bf16x8 bfr = *reinterpret_cast<const bf16x8*>(W1s + (((nt * 9 + kt) << 6) + lane) * 8);
        #pragma unroll
        for (int m = 0; m < 4; m++) {
          const bf16x8 af = *reinterpret_cast<const bf16x8*>(bufA + (m * 16 + l_lo) * 296 + kt * 32 + l_hi * 8);
          acc1[m] = __builtin_amdgcn_mfma_f32_16x16x32_bf16(af, bfr, acc1[m], 0, 0, 0);
        }
      }
    }
    __syncthreads();   // all waves done with GEMM2(c-1) reads of bufB
    if (nt < 34) {
      const int coln = nt * 16 + l_lo;
      const float bias = (coln < 530) ? b1[coln] : 0.f;
      #pragma unroll
      for (int m = 0; m < 4; m++)
        #pragma unroll
        for (int r = 0; r < 4; r++) {
          const int row = m * 16 + l_hi * 4 + r;
          bufB[row * 136 + w * 16 + l_lo] = f2b(silu_f(acc1[m][r] + bias));
        }
    }
    __syncthreads();   // Y1 chunk ready
    const int nk2 = (c < 4) ? 4 : 1;
    for (int j = 0; j < nk2; j++) {
      const int k2 = 4 * c + j;
      const bf16x8 bfr = *reinterpret_cast<const bf16x8*>(W2s + (((w * 17 + k2) << 6) + lane) * 8);
      #pragma unroll
      for (int m = 0; m < 4; m++) {
        const bf16x8 af = *reinterpret_cast<const bf16x8*>(bufB + (m * 16 + l_lo) * 136 + j * 32 + l_hi * 8);
        acc2[m] = __builtin_amdgcn_mfma_f32_16x16x32_bf16(af, bfr, acc2[m], 0, 0, 0);
      }
    }
  }
  __syncthreads();   // all GEMM2 reads of bufB done

  // ef = silu(acc2 + b2): write to bufB (A3) + atomic agg_h
  {
    const int coln = w * 16 + l_lo;
    const float bias = b2[coln];
    #pragma unroll
    for (int m = 0; m < 4; m++)
      #pragma unroll
      for (int r = 0; r < 4; r++) {
        const int el = m * 16 + l_hi * 4 + r;
        const float ef = silu_f(acc2[m][r] + bias);
        bufB[el * 136 + coln] = f2b(ef);
        atomicAdd(&agg_h[(size_t)row_s[el] * 128 + coln], ef);
      }
  }
  __syncthreads();

  // GEMM3: [64,128] x [128,256]; wave w owns n-tiles w, w+8
  f32x4 acc3[2][4];
  #pragma unroll
  for (int i = 0; i < 2; i++)
    #pragma unroll
    for (int m = 0; m < 4; m++) acc3[i][m] = {0.f, 0.f, 0.f, 0.f};
  for (int kt = 0; kt < 4; kt++) {
    bf16x8 af[4];
    #pragma unroll
    for (int m = 0; m < 4; m++)
      af[m] = *reinterpret_cast<const bf16x8*>(bufB + (m * 16 + l_lo) * 136 + kt * 32 + l_hi * 8);
    #pragma unroll
    for (int i = 0; i < 2; i++) {
      const int nt = w + 8 * i;
      const bf16x8 bfr = *reinterpret_cast<const bf16x8*>(WC1s + (((nt * 4 + kt) << 6) + lane) * 8);
      #pragma unroll
      for (int m = 0; m < 4; m++)
        acc3[i][m] = __builtin_amdgcn_mfma_f32_16x16x32_bf16(af[m], bfr, acc3[i][m], 0, 0, 0);
    }
  }
  // epi3 -> bufA (Y3 [64][264]); no overlap with bufB so no barrier before writes
  #pragma unroll
  for (int i = 0; i < 2; i++) {
    const int nt = w + 8 * i;
    const int coln = nt * 16 + l_lo;
    const float bias = bc1[coln];
    #pragma unroll
    for (int m = 0; m < 4; m++)
      #pragma unroll
      for (int r = 0; r < 4; r++) {
        const int row = m * 16 + l_hi * 4 + r;
        bufA[row * 264 + coln] = f2b(silu_f(acc3[i][m][r] + bias));
      }
  }
  __syncthreads();

  // GEMM4: [64,256] x [256,16] (cols 0..2 real); waves 0..3, m-tile = w
  if (w < 4) {
    f32x4 acc4 = {0.f, 0.f, 0.f, 0.f};
    for (int kt = 0; kt < 8; kt++) {
      const bf16x8 af = *reinterpret_cast<const bf16x8*>(bufA + (w * 16 + l_lo) * 264 + kt * 32 + l_hi * 8);
      const bf16x8 bfr = *reinterpret_cast<const bf16x8*>(WC2s + ((kt << 6) + lane) * 8);
      acc4 = __builtin_amdgcn_mfma_f32_16x16x32_bf16(af, bfr, acc4, 0, 0, 0);
    }
    if (l_lo < 3) {
      #pragma unroll
      for (int r = 0; r < 4; r++) phi_s[w * 16 + l_hi * 4 + r][l_lo] = acc4[r];
    }
  }
  __syncthreads();

  if (tid < 64) {
    const int node = row_s[tid];
    const float p0 = phi_s[tid][0], p1 = phi_s[tid][1], p2 = phi_s[tid][2];
    #pragma unroll
    for (int d = 0; d < 3; d++) {
      atomicAdd(&agg_c[(size_t)node * 9 + 0 + d], cd_s[tid][0 + d] * p0);
      atomicAdd(&agg_c[(size_t)node * 9 + 3 + d], cd_s[tid][3 + d] * p1);
      atomicAdd(&agg_c[(size_t)node * 9 + 6 + d], cd_s[tid][6 + d] * p2);
    }
    atomicAdd(&cnt[node], 1.f);
  }
}

// ---------------- node MLP ----------------
__global__ __launch_bounds__(512)
void node_kernel(const float* __restrict__ h, const u16* __restrict__ hb,
                 const float* __restrict__ agg_h,
                 const u16* __restrict__ WN1s, const float* __restrict__ nb1,
                 const u16* __restrict__ WN2s, const float* __restrict__ nb2,
                 float* __restrict__ out) {
  __shared__ __align__(16) u16 buf[64 * 520];  // A [64][264] then Y1 [64][520]
  const int tid = threadIdx.x;
  const int lane = tid & 63;
  const int w = tid >> 6;
  const int l_lo = lane & 15;
  const int l_hi = lane >> 4;
  const int n0 = blockIdx.x << 6;

  for (int q = tid; q < 1024; q += 512) {
    const int e = q >> 4, j = q & 15;
    const int row = n0 + e;
    int4 v;
    if (row < NN) v = *reinterpret_cast<const int4*>(hb + (size_t)row * 128 + j * 8);
    else { v.x = v.y = v.z = v.w = 0; }
    *reinterpret_cast<int4*>(buf + e * 264 + j * 8) = v;
  }
  for (int q = tid; q < 8192; q += 512) {
    const int e = q >> 7, k = q & 127;
    const int row = n0 + e;
    const float v = (row < NN) ? agg_h[(size_t)row * 128 + k] : 0.f;
    buf[e * 264 + 128 + k] = f2b(v);
  }
  __syncthreads();

  // GEMM5: [64,256] x [256,512]; wave w owns n-tiles w, w+8, w+16, w+24
  f32x4 acc[4][4];
  #pragma unroll
  for (int i = 0; i < 4; i++)
    #pragma unroll
    for (int m = 0; m < 4; m++) acc[i][m] = {0.f, 0.f, 0.f, 0.f};
  for (int kt = 0; kt < 8; kt++) {
    bf16x8 af[4];
    #pragma unroll
    for (int m = 0; m < 4; m++)
      af[m] = *reinterpret_cast<const bf16x8*>(buf + (m * 16 + l_lo) * 264 + kt * 32 + l_hi * 8);
    #pragma unroll
    for (int i = 0; i < 4; i++) {
      const int nt = w + 8 * i;
      const bf16x8 bfr = *reinterpret_cast<const bf16x8*>(WN1s + (((nt * 8 + kt) << 6) + lane) * 8);
      #pragma unroll
      for (int m = 0; m < 4; m++)
        acc[i][m] = __builtin_amdgcn_mfma_f32_16x16x32_bf16(af[m], bfr, acc[i][m], 0, 0, 0);
    }
  }
  __syncthreads();
  #pragma unroll
  for (int i = 0; i < 4; i++) {
    const int nt = w + 8 * i;
    const int coln = nt * 16 + l_lo;
    const float bias = nb1[coln];
    #pragma unroll
    for (int m = 0; m < 4; m++)
      #pragma unroll
      for (int r = 0; r < 4; r++) {
        const int row = m * 16 + l_hi * 4 + r;
        buf[row * 520 + coln] = f2b(silu_f(acc[i][m][r] + bias));
      }
  }
  __syncthreads();

  // GEMM6: [64,512] x [512,128]; wave w owns n-tile w
  f32x4 acc2[4];
  #pragma unroll
  for (int m = 0; m < 4; m++) acc2[m] = {0.f, 0.f, 0.f, 0.f};
  for (int kt = 0; kt < 16; kt++) {
    const bf16x8 bfr = *reinterpret_cast<const bf16x8*>(WN2s + (((w * 16 + kt) << 6) + lane) * 8);
    #pragma unroll
    for (int m = 0; m < 4; m++) {
      const bf16x8 af = *reinterpret_cast<const bf16x8*>(buf + (m * 16 + l_lo) * 520 + kt * 32 + l_hi * 8);
      acc2[m] = __builtin_amdgcn_mfma_f32_16x16x32_bf16(af, bfr, acc2[m], 0, 0, 0);
    }
  }
  {
    const int coln = w * 16 + l_lo;
    const float bias = nb2[coln];
    #pragma unroll
    for (int m = 0; m < 4; m++)
      #pragma unroll
      for (int r = 0; r < 4; r++) {
        const int row = n0 + m * 16 + l_hi * 4 + r;
        if (row < NN)
          out[(size_t)row * 128 + coln] = h[(size_t)row * 128 + coln] + silu_f(acc2[m][r] + bias);
      }
  }
}

__global__ void coord_kernel(const float* __restrict__ coord, const float* __restrict__ agg_c,
                             const float* __restrict__ cnt, float* __restrict__ out) {
  int i = blockIdx.x * 256 + threadIdx.x;
  if (i < NN * 9) {
    float c = fmaxf(cnt[i / 9], 1.f);
    float v = agg_c[i] / c;
    v = fminf(fmaxf(v, -10.f), 10.f);
    out[i] = coord[i] + v;
  }
}

extern "C" void kernel_launch(void* const* d_in, const int* in_sizes, int n_in,
                              void* d_out, int out_size, void* d_ws, size_t ws_size,
                              hipStream_t stream) {
  (void)in_sizes; (void)n_in; (void)out_size; (void)ws_size;
  const float* h     = (const float*)d_in[0];
  const int*   eidx  = (const int*)d_in[1];
  const float* coord = (const float*)d_in[2];
  const float* eW1 = (const float*)d_in[3];  const float* eb1 = (const float*)d_in[4];
  const float* eW2 = (const float*)d_in[5];  const float* eb2 = (const float*)d_in[6];
  const float* nW1 = (const float*)d_in[7];  const float* nb1 = (const float*)d_in[8];
  const float* nW2 = (const float*)d_in[9];  const float* nb2 = (const float*)d_in[10];
  const float* cW1 = (const float*)d_in[11]; const float* cb1 = (const float*)d_in[12];
  const float* cW2 = (const float*)d_in[13];

  char* ws = (char*)d_ws;
  u16* W1s  = (u16*)(ws + OFF_W1);
  u16* W2s  = (u16*)(ws + OFF_W2);
  u16* WC1s = (u16*)(ws + OFF_WC1);
  u16* WC2s = (u16*)(ws + OFF_WC2);
  u16* WN1s = (u16*)(ws + OFF_WN1);
  u16* WN2s = (u16*)(ws + OFF_WN2);
  u16* hb   = (u16*)(ws + OFF_HB);
  float* agg_h = (float*)(ws + OFF_AGGH);
  float* agg_c = (float*)(ws + OFF_AGGC);
  float* cnt   = (float*)(ws + OFF_CNT);
  float* out   = (float*)d_out;

  hipMemsetAsync(ws + OFF_AGGH, 0, SZ_AGGH + SZ_AGGC + SZ_CNT, stream);

  swz_kernel<<<9 * 34 * 2, 256, 0, stream>>>(eW1, W1s, 265, 530, 9, 34);
  swz_kernel<<<17 * 8 * 2, 256, 0, stream>>>(eW2, W2s, 530, 128, 17, 8);
  swz_kernel<<<4 * 16 * 2, 256, 0, stream>>>(cW1, WC1s, 128, 256, 4, 16);
  swz_kernel<<<8 * 1 * 2, 256, 0, stream>>>(cW2, WC2s, 256, 3, 8, 1);
  swz_kernel<<<8 * 32 * 2, 256, 0, stream>>>(nW1, WN1s, 256, 512, 8, 32);
  swz_kernel<<<16 * 8 * 2, 256, 0, stream>>>(nW2, WN2s, 512, 128, 16, 8);
  tob16_kernel<<<(NN * 128 + 255) / 256, 256, 0, stream>>>(h, hb, NN * 128);

  edge_kernel<<<NE / 64, 512, 0, stream>>>(hb, eidx, coord, W1s, eb1, W2s, eb2,
                                           WC1s, cb1, WC2s, agg_h, agg_c, cnt);
  node_kernel<<<(NN + 63) / 64, 512, 0, stream>>>(h, hb, agg_h, WN1s, nb1, WN2s, nb2, out);
  coord_kernel<<<(NN * 9 + 255) / 256, 256, 0, stream>>>(coord, agg_c, cnt, out + (size_t)NN * 128);
}